// Round 7
// baseline (746.760 us; speedup 1.0000x reference)
//
#include <hip/hip_runtime.h>
#include <hip/hip_bf16.h>

// Relative-position causal attention, B=4 H=16 Q=K=1024 D=64 (fp32 in/out).
// d_out = [output (BH*Q*D) | p_attn (BH*Q*K)] fp32.
// K1 content scores -> K2 rel+exp (triangular grid: 8 k-slices x active 4-q
// tiles; wave = 1 q x 8 static k-steps, 4-deep register prefetch => ~512B in
// flight/wave) -> K3 P@V (normalizes P in place) -> K4 P@bigr_v.

#define BH 64
#define SQ 1024
#define SK 1024
#define DH 64
#define SCALE 0.125f

typedef __attribute__((ext_vector_type(4))) float f32x4;
typedef __attribute__((ext_vector_type(8))) unsigned short ushort8;
typedef __attribute__((ext_vector_type(8))) __bf16 bf16x8;

static __device__ inline unsigned short f2bf(float x) {
    unsigned u = __float_as_uint(x);
    unsigned r = u + 0x7FFFu + ((u >> 16) & 1u);
    return (unsigned short)(r >> 16);
}
static __device__ inline float bf2f(unsigned short s) {
    return __uint_as_float(((unsigned)s) << 16);
}

struct Frag2 { bf16x8 h, l; };

static __device__ inline Frag2 load_split(const float* __restrict__ p) {
    float4 x0 = *reinterpret_cast<const float4*>(p);
    float4 x1 = *reinterpret_cast<const float4*>(p + 4);
    float v[8] = {x0.x, x0.y, x0.z, x0.w, x1.x, x1.y, x1.z, x1.w};
    ushort8 uh, ul;
#pragma unroll
    for (int j = 0; j < 8; ++j) {
        unsigned short h = f2bf(v[j]);
        float r = v[j] - bf2f(h);
        uh[j] = h;
        ul[j] = f2bf(r);
    }
    Frag2 f;
    f.h = __builtin_bit_cast(bf16x8, uh);
    f.l = __builtin_bit_cast(bf16x8, ul);
    return f;
}

static __device__ inline bf16x8 pack_bf8(float4 x0, float4 x1) {
    float v[8] = {x0.x, x0.y, x0.z, x0.w, x1.x, x1.y, x1.z, x1.w};
    ushort8 u;
#pragma unroll
    for (int j = 0; j < 8; ++j) u[j] = f2bf(v[j]);
    return __builtin_bit_cast(bf16x8, u);
}

static __device__ inline bf16x8 load_bf8(const float* __restrict__ p) {
    float4 x0 = *reinterpret_cast<const float4*>(p);
    float4 x1 = *reinterpret_cast<const float4*>(p + 4);
    return pack_bf8(x0, x1);
}

static __device__ inline bf16x8 load_bf8_strided(const float* __restrict__ p, int stride) {
    ushort8 u;
#pragma unroll
    for (int j = 0; j < 8; ++j) u[j] = f2bf(p[(size_t)j * stride]);
    return __builtin_bit_cast(bf16x8, u);
}

#define MFMA(a, b, c) __builtin_amdgcn_mfma_f32_16x16x32_bf16((a), (b), (c), 0, 0, 0)

static __device__ inline f32x4 mfma_split(const Frag2& a, const Frag2& b, f32x4 c) {
    c = MFMA(a.h, b.h, c);
    c = MFMA(a.h, b.l, c);
    c = MFMA(a.l, b.h, c);
    return c;
}

// ---------------- K1: content scores Q@K^T * scale -> P region (zeros above diag)
__global__ __launch_bounds__(256) void k_scores(const float* __restrict__ q,
                                                const float* __restrict__ k,
                                                float* __restrict__ P) {
    const int kt = blockIdx.x, qt = blockIdx.y, bh = blockIdx.z;
    const int tid = threadIdx.x;
    const int kbase = kt * 64;
    if (kbase > qt * 64 + 63) {  // fully masked tile: zeros
        const int row = qt * 64 + (tid >> 2);
        float4 z = {0.f, 0.f, 0.f, 0.f};
        float4* dst = reinterpret_cast<float4*>(
            &P[((size_t)bh * SQ + row) * SK + kbase + (tid & 3) * 16]);
        dst[0] = z; dst[1] = z; dst[2] = z; dst[3] = z;
        return;
    }
    const int w = tid >> 6, l = tid & 63;
    const int lm = l & 15, lg = l >> 4;
    const int q0 = qt * 64 + w * 16;
    const float* qrow = q + ((size_t)bh * SQ + q0 + lm) * DH + lg * 8;
    Frag2 a0 = load_split(qrow);
    Frag2 a1 = load_split(qrow + 32);
#pragma unroll
    for (int nt = 0; nt < 4; ++nt) {
        const int kc = kbase + nt * 16 + lm;
        f32x4 acc = {0.f, 0.f, 0.f, 0.f};
        if (kbase + nt * 16 <= q0 + 15) {
            const float* krow = k + ((size_t)bh * SK + kc) * DH + lg * 8;
            Frag2 b0 = load_split(krow);
            Frag2 b1 = load_split(krow + 32);
            acc = mfma_split(a0, b0, acc);
            acc = mfma_split(a1, b1, acc);
        }
#pragma unroll
        for (int r = 0; r < 4; ++r) {
            const int qq = q0 + lg * 4 + r;
            float v = (kc <= qq) ? acc[r] * SCALE : 0.f;
            P[((size_t)bh * SQ + qq) * SK + kc] = v;
        }
    }
}

// ---------------- K2: triangular (ksl x 4q-tile) grid; wave = 1 q, 8 static
// k-steps of 16, 4-deep register prefetch. A = bigr_k rows (bf16), B = query
// bh-cols (split bf16). C lane map: k = k0+lg*4+r, bh = nt*16+lm.
struct SB { float4 a[4]; float4 p[4]; };

static __device__ inline void k2_issue(SB& B, const float* __restrict__ bk,
                                       float* const* prow, int k0, int lm, int lg) {
    const float* arow = bk + (size_t)(k0 + lm) * DH + lg * 8;
    B.a[0] = *reinterpret_cast<const float4*>(arow);
    B.a[1] = *reinterpret_cast<const float4*>(arow + 4);
    B.a[2] = *reinterpret_cast<const float4*>(arow + 32);
    B.a[3] = *reinterpret_cast<const float4*>(arow + 36);
#pragma unroll
    for (int nt = 0; nt < 4; ++nt)
        B.p[nt] = *reinterpret_cast<const float4*>(prow[nt] + k0 + lg * 4);
}

static __device__ inline void k2_compute(const SB& B, const Frag2* qh0, const Frag2* qh1,
                                         float* const* prow, int k0, int lg, int KE,
                                         float* lsum) {
    bf16x8 alo = pack_bf8(B.a[0], B.a[1]);
    bf16x8 ahi = pack_bf8(B.a[2], B.a[3]);
    const int kq = k0 + lg * 4;
#pragma unroll
    for (int nt = 0; nt < 4; ++nt) {
        f32x4 acc = {0.f, 0.f, 0.f, 0.f};
        acc = MFMA(alo, qh0[nt].h, acc);
        acc = MFMA(alo, qh0[nt].l, acc);
        acc = MFMA(ahi, qh1[nt].h, acc);
        acc = MFMA(ahi, qh1[nt].l, acc);
        const float4 c = B.p[nt];
        float cv[4] = {c.x, c.y, c.z, c.w};
        float ov[4];
#pragma unroll
        for (int r = 0; r < 4; ++r) {
            float e = (kq + r < KE) ? __expf(cv[r] + acc[r] * SCALE) : 0.f;
            ov[r] = e;
            lsum[nt] += e;
        }
        float4 o;
        o.x = ov[0]; o.y = ov[1]; o.z = ov[2]; o.w = ov[3];
        *reinterpret_cast<float4*>(prow[nt] + kq) = o;
    }
}

__global__ __launch_bounds__(256, 8) void k_rel_exp(const float* __restrict__ query,
                                                    const float* __restrict__ bigr_k,
                                                    float* __restrict__ P,
                                                    float* __restrict__ partial) {
    const int bid = blockIdx.x;
    int ksl, idx;  // triangular map: slice ksl has 256-32*ksl active q-tiles
    if (bid < 256)       { ksl = 0; idx = bid; }
    else if (bid < 480)  { ksl = 1; idx = bid - 256; }
    else if (bid < 672)  { ksl = 2; idx = bid - 480; }
    else if (bid < 832)  { ksl = 3; idx = bid - 672; }
    else if (bid < 960)  { ksl = 4; idx = bid - 832; }
    else if (bid < 1056) { ksl = 5; idx = bid - 960; }
    else if (bid < 1120) { ksl = 6; idx = bid - 1056; }
    else                 { ksl = 7; idx = bid - 1120; }
    const int qt = 255 - idx;  // big q first
    const int tid = threadIdx.x;
    const int w = tid >> 6, l = tid & 63;
    const int lm = l & 15, lg = l >> 4;
    const int q = qt * 4 + w;      // this wave's q (>= kbase by construction)
    const int KE = q + 1;
    const int kbase = ksl * 128;

    Frag2 qh0[4], qh1[4];
    float* prow[4];
#pragma unroll
    for (int nt = 0; nt < 4; ++nt) {
        const int bh = nt * 16 + lm;
        const float* qrow = query + ((size_t)bh * SQ + q) * DH + lg * 8;
        qh0[nt] = load_split(qrow);
        qh1[nt] = load_split(qrow + 32);
        prow[nt] = P + ((size_t)bh * SQ + q) * SK;
    }
    const float* bk = bigr_k + (size_t)q * SK * DH;
    float lsum[4] = {0.f, 0.f, 0.f, 0.f};

    // 8 unconditional k-steps (writes beyond KE are zeros -> correct causal mask),
    // 4-deep static prefetch pipeline.
    SB b0, b1, b2, b3;
    k2_issue(b0, bk, prow, kbase +   0, lm, lg);
    k2_issue(b1, bk, prow, kbase +  16, lm, lg);
    k2_issue(b2, bk, prow, kbase +  32, lm, lg);
    k2_issue(b3, bk, prow, kbase +  48, lm, lg);
    k2_compute(b0, qh0, qh1, prow, kbase +   0, lg, KE, lsum);
    k2_issue(b0, bk, prow, kbase +  64, lm, lg);
    k2_compute(b1, qh0, qh1, prow, kbase +  16, lg, KE, lsum);
    k2_issue(b1, bk, prow, kbase +  80, lm, lg);
    k2_compute(b2, qh0, qh1, prow, kbase +  32, lg, KE, lsum);
    k2_issue(b2, bk, prow, kbase +  96, lm, lg);
    k2_compute(b3, qh0, qh1, prow, kbase +  48, lg, KE, lsum);
    k2_issue(b3, bk, prow, kbase + 112, lm, lg);
    k2_compute(b0, qh0, qh1, prow, kbase +  64, lg, KE, lsum);
    k2_compute(b1, qh0, qh1, prow, kbase +  80, lg, KE, lsum);
    k2_compute(b2, qh0, qh1, prow, kbase +  96, lg, KE, lsum);
    k2_compute(b3, qh0, qh1, prow, kbase + 112, lg, KE, lsum);

    // reduce over lg (xor 16, 32) -> per-bh sums; lanes l<16 write
    float* pp = partial + ((size_t)ksl * SQ + q) * 64;
#pragma unroll
    for (int nt = 0; nt < 4; ++nt) {
        float v = lsum[nt];
        v += __shfl_xor(v, 16);
        v += __shfl_xor(v, 32);
        lsum[nt] = v;
    }
    if (l < 16) {
#pragma unroll
        for (int nt = 0; nt < 4; ++nt) pp[nt * 16 + l] = lsum[nt];
    }
}

// ---------------- K3: out = (1/sum) * e @ V ; normalizes P in place as it streams.
__global__ __launch_bounds__(256) void k_pv(float* __restrict__ P,
                                            const float* __restrict__ V,
                                            const float* __restrict__ partial,
                                            float* __restrict__ out) {
    const int qt = 15 - (int)blockIdx.x;  // big tiles first
    const int bh = blockIdx.y;
    const int tid = threadIdx.x;
    const int w = tid >> 6, l = tid & 63;
    const int lm = l & 15, lg = l >> 4;
    const int q0 = qt * 64 + w * 16;

    float wrecip;
    {
        const size_t b = (size_t)(q0 + lm) * 64 + bh;
        float s = 0.f;
#pragma unroll
        for (int sl = 0; sl < 8; ++sl) s += partial[(size_t)sl * SQ * 64 + b];
        wrecip = 1.0f / s;
    }
    float orecip[4];
#pragma unroll
    for (int r = 0; r < 4; ++r) {
        const size_t b = (size_t)(q0 + lg * 4 + r) * 64 + bh;
        float s = 0.f;
#pragma unroll
        for (int sl = 0; sl < 8; ++sl) s += partial[(size_t)sl * SQ * 64 + b];
        orecip[r] = 1.0f / s;
    }

    f32x4 acc[4] = {{0.f,0.f,0.f,0.f},{0.f,0.f,0.f,0.f},{0.f,0.f,0.f,0.f},{0.f,0.f,0.f,0.f}};
    const int kend = q0 + 16;
    for (int k0 = 0; k0 < kend; k0 += 32) {
        float* arow = P + ((size_t)bh * SQ + q0 + lm) * SK + k0 + lg * 8;
        float4 x0 = *reinterpret_cast<const float4*>(arow);
        float4 x1 = *reinterpret_cast<const float4*>(arow + 4);
        float4 y0 = {x0.x * wrecip, x0.y * wrecip, x0.z * wrecip, x0.w * wrecip};
        float4 y1 = {x1.x * wrecip, x1.y * wrecip, x1.z * wrecip, x1.w * wrecip};
        *reinterpret_cast<float4*>(arow) = y0;
        *reinterpret_cast<float4*>(arow + 4) = y1;
        bf16x8 a = pack_bf8(x0, x1);
#pragma unroll
        for (int nt = 0; nt < 4; ++nt) {
            const float* bcol = V + ((size_t)bh * SK + k0 + lg * 8) * DH + nt * 16 + lm;
            bf16x8 b = load_bf8_strided(bcol, DH);
            acc[nt] = MFMA(a, b, acc[nt]);
        }
    }
#pragma unroll
    for (int nt = 0; nt < 4; ++nt)
#pragma unroll
        for (int r = 0; r < 4; ++r)
            out[((size_t)bh * SQ + q0 + lg * 4 + r) * DH + nt * 16 + lm] =
                acc[nt][r] * orecip[r];
}

// ---------------- K4: out += P_norm @ bigr_v[q] (per q, all bh); LDS staging
__global__ __launch_bounds__(256) void k_pr(const float* __restrict__ P,
                                            const float* __restrict__ bigr_v,
                                            float* __restrict__ out) {
    __shared__ float vt[64][36];
    const int qpos = SQ - 1 - (int)blockIdx.x;
    const int tid = threadIdx.x;
    const int w = tid >> 6, l = tid & 63;
    const int lm = l & 15, lg = l >> 4;
    const int bh0 = w * 16;
    const int skk = tid & 31, sdd = (tid >> 5) * 8;
    f32x4 acc[4] = {{0.f,0.f,0.f,0.f},{0.f,0.f,0.f,0.f},{0.f,0.f,0.f,0.f},{0.f,0.f,0.f,0.f}};
    const int kend = qpos + 1;
    for (int k0 = 0; k0 < kend; k0 += 32) {
        __syncthreads();
        {
            const float* src = bigr_v + ((size_t)qpos * SK + k0 + skk) * DH + sdd;
            float4 v0 = *reinterpret_cast<const float4*>(src);
            float4 v1 = *reinterpret_cast<const float4*>(src + 4);
            vt[sdd + 0][skk] = v0.x; vt[sdd + 1][skk] = v0.y;
            vt[sdd + 2][skk] = v0.z; vt[sdd + 3][skk] = v0.w;
            vt[sdd + 4][skk] = v1.x; vt[sdd + 5][skk] = v1.y;
            vt[sdd + 6][skk] = v1.z; vt[sdd + 7][skk] = v1.w;
        }
        __syncthreads();
        const float* arow = P + ((size_t)(bh0 + lm) * SQ + qpos) * SK + k0 + lg * 8;
        bf16x8 a = load_bf8(arow);
#pragma unroll
        for (int nt = 0; nt < 4; ++nt) {
            const float* bp = &vt[nt * 16 + lm][lg * 8];
            float4 u0 = *reinterpret_cast<const float4*>(bp);
            float4 u1 = *reinterpret_cast<const float4*>(bp + 4);
            acc[nt] = MFMA(a, pack_bf8(u0, u1), acc[nt]);
        }
    }
#pragma unroll
    for (int nt = 0; nt < 4; ++nt)
#pragma unroll
        for (int r = 0; r < 4; ++r) {
            const size_t o = ((size_t)(bh0 + lg * 4 + r) * SQ + qpos) * DH + nt * 16 + lm;
            out[o] += acc[nt][r];
        }
}

extern "C" void kernel_launch(void* const* d_in, const int* in_sizes, int n_in,
                              void* d_out, int out_size, void* d_ws, size_t ws_size,
                              hipStream_t stream) {
    const float* query  = (const float*)d_in[0];
    const float* key    = (const float*)d_in[1];
    const float* value  = (const float*)d_in[2];
    const float* bigr_k = (const float*)d_in[3];
    const float* bigr_v = (const float*)d_in[4];
    float* out = (float*)d_out;                       // BH*SQ*DH
    float* P   = out + (size_t)BH * SQ * DH;          // BH*SQ*SK
    float* partial = (float*)d_ws;                    // [8][SQ][BH] fp32 = 2 MB

    hipMemsetAsync(partial, 0, (size_t)8 * SQ * 64 * sizeof(float), stream);
    k_scores<<<dim3(16, 16, BH), 256, 0, stream>>>(query, key, P);
    k_rel_exp<<<dim3(1152), 256, 0, stream>>>(query, bigr_k, P, partial);
    k_pv<<<dim3(16, BH), 256, 0, stream>>>(P, value, partial, out);
    k_pr<<<dim3(SQ), 256, 0, stream>>>(P, bigr_v, out);
}

// Round 8
// 502.473 us; speedup vs baseline: 1.4862x; 1.4862x over previous
//
#include <hip/hip_runtime.h>
#include <hip/hip_bf16.h>

// Relative-position causal attention, B=4 H=16 Q=K=1024 D=64 (fp32 in/out).
// d_out = [output (BH*Q*D) | p_attn (BH*Q*K)] fp32.
// K1 content scores -> K2 rel+exp (block per q; bigr_k staged via
// global_load_lds into swizzled LDS double buffer; full row sum) ->
// K3 P@V (normalizes P in place) -> K4 P@bigr_v.

#define BH 64
#define SQ 1024
#define SK 1024
#define DH 64
#define SCALE 0.125f

typedef __attribute__((ext_vector_type(4))) float f32x4;
typedef __attribute__((ext_vector_type(8))) unsigned short ushort8;
typedef __attribute__((ext_vector_type(8))) __bf16 bf16x8;

static __device__ inline unsigned short f2bf(float x) {
    unsigned u = __float_as_uint(x);
    unsigned r = u + 0x7FFFu + ((u >> 16) & 1u);
    return (unsigned short)(r >> 16);
}
static __device__ inline float bf2f(unsigned short s) {
    return __uint_as_float(((unsigned)s) << 16);
}

struct Frag2 { bf16x8 h, l; };

static __device__ inline Frag2 load_split(const float* __restrict__ p) {
    float4 x0 = *reinterpret_cast<const float4*>(p);
    float4 x1 = *reinterpret_cast<const float4*>(p + 4);
    float v[8] = {x0.x, x0.y, x0.z, x0.w, x1.x, x1.y, x1.z, x1.w};
    ushort8 uh, ul;
#pragma unroll
    for (int j = 0; j < 8; ++j) {
        unsigned short h = f2bf(v[j]);
        float r = v[j] - bf2f(h);
        uh[j] = h;
        ul[j] = f2bf(r);
    }
    Frag2 f;
    f.h = __builtin_bit_cast(bf16x8, uh);
    f.l = __builtin_bit_cast(bf16x8, ul);
    return f;
}

static __device__ inline bf16x8 pack_bf8(float4 x0, float4 x1) {
    float v[8] = {x0.x, x0.y, x0.z, x0.w, x1.x, x1.y, x1.z, x1.w};
    ushort8 u;
#pragma unroll
    for (int j = 0; j < 8; ++j) u[j] = f2bf(v[j]);
    return __builtin_bit_cast(bf16x8, u);
}

static __device__ inline bf16x8 load_bf8(const float* __restrict__ p) {
    float4 x0 = *reinterpret_cast<const float4*>(p);
    float4 x1 = *reinterpret_cast<const float4*>(p + 4);
    return pack_bf8(x0, x1);
}

static __device__ inline bf16x8 load_bf8_strided(const float* __restrict__ p, int stride) {
    ushort8 u;
#pragma unroll
    for (int j = 0; j < 8; ++j) u[j] = f2bf(p[(size_t)j * stride]);
    return __builtin_bit_cast(bf16x8, u);
}

#define MFMA(a, b, c) __builtin_amdgcn_mfma_f32_16x16x32_bf16((a), (b), (c), 0, 0, 0)

static __device__ inline f32x4 mfma_split(const Frag2& a, const Frag2& b, f32x4 c) {
    c = MFMA(a.h, b.h, c);
    c = MFMA(a.h, b.l, c);
    c = MFMA(a.l, b.h, c);
    return c;
}

// async global -> LDS, 16B per lane; lds dest is wave-uniform base + lane*16
#define GLLD(g, s)                                                              \
    __builtin_amdgcn_global_load_lds(                                           \
        (const __attribute__((address_space(1))) void*)(g),                     \
        (__attribute__((address_space(3))) void*)(s), 16, 0, 0)

// ---------------- K1: content scores Q@K^T * scale -> P region (zeros above diag)
__global__ __launch_bounds__(256) void k_scores(const float* __restrict__ q,
                                                const float* __restrict__ k,
                                                float* __restrict__ P) {
    const int kt = blockIdx.x, qt = blockIdx.y, bh = blockIdx.z;
    const int tid = threadIdx.x;
    const int kbase = kt * 64;
    if (kbase > qt * 64 + 63) {  // fully masked tile: zeros
        const int row = qt * 64 + (tid >> 2);
        float4 z = {0.f, 0.f, 0.f, 0.f};
        float4* dst = reinterpret_cast<float4*>(
            &P[((size_t)bh * SQ + row) * SK + kbase + (tid & 3) * 16]);
        dst[0] = z; dst[1] = z; dst[2] = z; dst[3] = z;
        return;
    }
    const int w = tid >> 6, l = tid & 63;
    const int lm = l & 15, lg = l >> 4;
    const int q0 = qt * 64 + w * 16;
    const float* qrow = q + ((size_t)bh * SQ + q0 + lm) * DH + lg * 8;
    Frag2 a0 = load_split(qrow);
    Frag2 a1 = load_split(qrow + 32);
#pragma unroll
    for (int nt = 0; nt < 4; ++nt) {
        const int kc = kbase + nt * 16 + lm;
        f32x4 acc = {0.f, 0.f, 0.f, 0.f};
        if (kbase + nt * 16 <= q0 + 15) {
            const float* krow = k + ((size_t)bh * SK + kc) * DH + lg * 8;
            Frag2 b0 = load_split(krow);
            Frag2 b1 = load_split(krow + 32);
            acc = mfma_split(a0, b0, acc);
            acc = mfma_split(a1, b1, acc);
        }
#pragma unroll
        for (int r = 0; r < 4; ++r) {
            const int qq = q0 + lg * 4 + r;
            float v = (kc <= qq) ? acc[r] * SCALE : 0.f;
            P[((size_t)bh * SQ + qq) * SK + kc] = v;
        }
    }
}

// ---------------- K2: block per q. bigr_k[q] staged in 64k x 64d tiles via
// global_load_lds into LDS double buffer (source pre-swizzled: chunk ^= row&7).
// Wave w computes within-tile k rows [w*16, w*16+16) for all 64 bh.
// A = bigr_k rows (single bf16 from LDS), B = query bh-cols (split bf16).
// C lane map: k = kq + r, bh = nt*16 + lm.
__global__ __launch_bounds__(256, 4) void k_rel_exp(const float* __restrict__ query,
                                                    const float* __restrict__ bigr_k,
                                                    float* __restrict__ P,
                                                    float* __restrict__ partial) {
    __shared__ float4 buf[2][1024];  // 2 x 16 KB: [tile row 0..63][chunk 0..15]
    __shared__ float red[4][64];
    const int q = SQ - 1 - (int)blockIdx.x;  // big rows first
    const int KE = q + 1;
    const int nt_ = (KE + 63) >> 6;
    const int tid = threadIdx.x;
    const int w = tid >> 6, l = tid & 63;
    const int lm = l & 15, lg = l >> 4;

    // query fragments (all 64 bh) + P row pointers
    Frag2 qh0[4], qh1[4];
    float* prow[4];
#pragma unroll
    for (int nt = 0; nt < 4; ++nt) {
        const int bh = nt * 16 + lm;
        const float* qrow = query + ((size_t)bh * SQ + q) * DH + lg * 8;
        qh0[nt] = load_split(qrow);
        qh1[nt] = load_split(qrow + 32);
        prow[nt] = P + ((size_t)bh * SQ + q) * SK;
    }
    const float* bk = bigr_k + (size_t)q * SK * DH;
    float lsum[4] = {0.f, 0.f, 0.f, 0.f};

    // stage tile t into buf[b]: 4 glld rounds per wave, source pre-swizzled
#define K2_STAGE(t, b)                                                          \
    do {                                                                        \
        const float* bkt = bk + (size_t)(t) * 64 * DH;                          \
        _Pragma("unroll")                                                       \
        for (int j = 0; j < 4; ++j) {                                           \
            const int idx = w * 256 + j * 64 + l; /* 16B-chunk index in tile */ \
            const int row = idx >> 4;                                           \
            const int g = (idx & 15) ^ (row & 7);                               \
            const float* src = bkt + (size_t)row * DH + g * 4;                  \
            GLLD(src, &buf[b][w * 256 + j * 64]);                               \
        }                                                                       \
    } while (0)

    K2_STAGE(0, 0);
    float4 pc[4];
#pragma unroll 1
    for (int t = 0; t < nt_; ++t) {
        if (t + 1 < nt_) K2_STAGE(t + 1, (t + 1) & 1);
        const int kq = t * 64 + w * 16 + lg * 4;
        // issue P content loads for THIS tile; drained by the barrier below
#pragma unroll
        for (int nt = 0; nt < 4; ++nt)
            pc[nt] = *reinterpret_cast<const float4*>(prow[nt] + kq);
        __syncthreads();  // drains glld(t) [+t+1] and pc loads
        // A fragments from swizzled LDS
        const float4* L = buf[t & 1];
        const int R = w * 16 + lm;   // within-tile k row
        const int sw = lm & 7;
        float4 f0 = L[R * 16 + ((2 * lg) ^ sw)];
        float4 f1 = L[R * 16 + ((2 * lg + 1) ^ sw)];
        float4 f2 = L[R * 16 + ((8 + 2 * lg) ^ sw)];
        float4 f3 = L[R * 16 + ((9 + 2 * lg) ^ sw)];
        bf16x8 alo = pack_bf8(f0, f1);
        bf16x8 ahi = pack_bf8(f2, f3);
#pragma unroll
        for (int nt = 0; nt < 4; ++nt) {
            f32x4 acc = {0.f, 0.f, 0.f, 0.f};
            acc = MFMA(alo, qh0[nt].h, acc);
            acc = MFMA(alo, qh0[nt].l, acc);
            acc = MFMA(ahi, qh1[nt].h, acc);
            acc = MFMA(ahi, qh1[nt].l, acc);
            const float4 c = pc[nt];
            float cv[4] = {c.x, c.y, c.z, c.w};
            float ov[4];
#pragma unroll
            for (int r = 0; r < 4; ++r) {
                float e = (kq + r < KE) ? __expf(cv[r] + acc[r] * SCALE) : 0.f;
                ov[r] = e;
                lsum[nt] += e;
            }
            float4 o;
            o.x = ov[0]; o.y = ov[1]; o.z = ov[2]; o.w = ov[3];
            *reinterpret_cast<float4*>(prow[nt] + kq) = o;
        }
        __syncthreads();  // all waves done reading buf[t&1] before restage
    }
#undef K2_STAGE

    // row-sum reduce: over lg (shfl), then over waves (LDS)
#pragma unroll
    for (int nt = 0; nt < 4; ++nt) {
        float v = lsum[nt];
        v += __shfl_xor(v, 16);
        v += __shfl_xor(v, 32);
        if (l < 16) red[w][nt * 16 + l] = v;
    }
    __syncthreads();
    if (tid < 64)
        partial[(size_t)q * 64 + tid] =
            red[0][tid] + red[1][tid] + red[2][tid] + red[3][tid];
}

// ---------------- K3: out = (1/sum) * e @ V ; normalizes P in place as it streams.
__global__ __launch_bounds__(256) void k_pv(float* __restrict__ P,
                                            const float* __restrict__ V,
                                            const float* __restrict__ partial,
                                            float* __restrict__ out) {
    const int qt = 15 - (int)blockIdx.x;  // big tiles first
    const int bh = blockIdx.y;
    const int tid = threadIdx.x;
    const int w = tid >> 6, l = tid & 63;
    const int lm = l & 15, lg = l >> 4;
    const int q0 = qt * 64 + w * 16;

    const float wrecip = 1.0f / partial[(size_t)(q0 + lm) * 64 + bh];
    float orecip[4];
#pragma unroll
    for (int r = 0; r < 4; ++r)
        orecip[r] = 1.0f / partial[(size_t)(q0 + lg * 4 + r) * 64 + bh];

    f32x4 acc[4] = {{0.f,0.f,0.f,0.f},{0.f,0.f,0.f,0.f},{0.f,0.f,0.f,0.f},{0.f,0.f,0.f,0.f}};
    const int kend = q0 + 16;
    for (int k0 = 0; k0 < kend; k0 += 32) {
        float* arow = P + ((size_t)bh * SQ + q0 + lm) * SK + k0 + lg * 8;
        float4 x0 = *reinterpret_cast<const float4*>(arow);
        float4 x1 = *reinterpret_cast<const float4*>(arow + 4);
        float4 y0 = {x0.x * wrecip, x0.y * wrecip, x0.z * wrecip, x0.w * wrecip};
        float4 y1 = {x1.x * wrecip, x1.y * wrecip, x1.z * wrecip, x1.w * wrecip};
        *reinterpret_cast<float4*>(arow) = y0;
        *reinterpret_cast<float4*>(arow + 4) = y1;
        bf16x8 a = pack_bf8(x0, x1);
#pragma unroll
        for (int nt = 0; nt < 4; ++nt) {
            const float* bcol = V + ((size_t)bh * SK + k0 + lg * 8) * DH + nt * 16 + lm;
            bf16x8 b = load_bf8_strided(bcol, DH);
            acc[nt] = MFMA(a, b, acc[nt]);
        }
    }
#pragma unroll
    for (int nt = 0; nt < 4; ++nt)
#pragma unroll
        for (int r = 0; r < 4; ++r)
            out[((size_t)bh * SQ + q0 + lg * 4 + r) * DH + nt * 16 + lm] =
                acc[nt][r] * orecip[r];
}

// ---------------- K4: out += P_norm @ bigr_v[q] (per q, all bh); LDS staging
__global__ __launch_bounds__(256) void k_pr(const float* __restrict__ P,
                                            const float* __restrict__ bigr_v,
                                            float* __restrict__ out) {
    __shared__ float vt[64][36];
    const int qpos = SQ - 1 - (int)blockIdx.x;
    const int tid = threadIdx.x;
    const int w = tid >> 6, l = tid & 63;
    const int lm = l & 15, lg = l >> 4;
    const int bh0 = w * 16;
    const int skk = tid & 31, sdd = (tid >> 5) * 8;
    f32x4 acc[4] = {{0.f,0.f,0.f,0.f},{0.f,0.f,0.f,0.f},{0.f,0.f,0.f,0.f},{0.f,0.f,0.f,0.f}};
    const int kend = qpos + 1;
    for (int k0 = 0; k0 < kend; k0 += 32) {
        __syncthreads();
        {
            const float* src = bigr_v + ((size_t)qpos * SK + k0 + skk) * DH + sdd;
            float4 v0 = *reinterpret_cast<const float4*>(src);
            float4 v1 = *reinterpret_cast<const float4*>(src + 4);
            vt[sdd + 0][skk] = v0.x; vt[sdd + 1][skk] = v0.y;
            vt[sdd + 2][skk] = v0.z; vt[sdd + 3][skk] = v0.w;
            vt[sdd + 4][skk] = v1.x; vt[sdd + 5][skk] = v1.y;
            vt[sdd + 6][skk] = v1.z; vt[sdd + 7][skk] = v1.w;
        }
        __syncthreads();
        const float* arow = P + ((size_t)(bh0 + lm) * SQ + qpos) * SK + k0 + lg * 8;
        bf16x8 a = load_bf8(arow);
#pragma unroll
        for (int nt = 0; nt < 4; ++nt) {
            const float* bp = &vt[nt * 16 + lm][lg * 8];
            float4 u0 = *reinterpret_cast<const float4*>(bp);
            float4 u1 = *reinterpret_cast<const float4*>(bp + 4);
            acc[nt] = MFMA(a, pack_bf8(u0, u1), acc[nt]);
        }
    }
#pragma unroll
    for (int nt = 0; nt < 4; ++nt)
#pragma unroll
        for (int r = 0; r < 4; ++r) {
            const size_t o = ((size_t)(bh0 + lg * 4 + r) * SQ + qpos) * DH + nt * 16 + lm;
            out[o] += acc[nt][r];
        }
}

extern "C" void kernel_launch(void* const* d_in, const int* in_sizes, int n_in,
                              void* d_out, int out_size, void* d_ws, size_t ws_size,
                              hipStream_t stream) {
    const float* query  = (const float*)d_in[0];
    const float* key    = (const float*)d_in[1];
    const float* value  = (const float*)d_in[2];
    const float* bigr_k = (const float*)d_in[3];
    const float* bigr_v = (const float*)d_in[4];
    float* out = (float*)d_out;                       // BH*SQ*DH
    float* P   = out + (size_t)BH * SQ * DH;          // BH*SQ*SK
    float* partial = (float*)d_ws;                    // [SQ][BH] fp32 = 256 KB

    k_scores<<<dim3(16, 16, BH), 256, 0, stream>>>(query, key, P);
    k_rel_exp<<<dim3(SQ), 256, 0, stream>>>(query, bigr_k, P, partial);
    k_pv<<<dim3(16, BH), 256, 0, stream>>>(P, value, partial, out);
    k_pr<<<dim3(SQ), 256, 0, stream>>>(P, bigr_v, out);
}

// Round 9
// 459.029 us; speedup vs baseline: 1.6268x; 1.0946x over previous
//
#include <hip/hip_runtime.h>
#include <hip/hip_bf16.h>

// Relative-position causal attention, B=4 H=16 Q=K=1024 D=64 (fp32 in/out).
// d_out = [output (BH*Q*D) | p_attn (BH*Q*K)] fp32.
// K1 k_scores: content scores via LDS-staged GEMM (zeros above diag).
// K2 k_rel_pr: per-q block; pass1 rel+exp (glld-staged bigr_k) + row sum;
//              pass2 normalize P in place (final p_attn) + out = Pn@bigr_v[q].
// K3 k_pv: out += Pn @ V (per bh, q-tiles).

#define BH 64
#define SQ 1024
#define SK 1024
#define DH 64
#define SCALE 0.125f

typedef __attribute__((ext_vector_type(4))) float f32x4;
typedef __attribute__((ext_vector_type(8))) unsigned short ushort8;
typedef __attribute__((ext_vector_type(8))) __bf16 bf16x8;

static __device__ inline unsigned short f2bf(float x) {
    unsigned u = __float_as_uint(x);
    unsigned r = u + 0x7FFFu + ((u >> 16) & 1u);
    return (unsigned short)(r >> 16);
}
static __device__ inline float bf2f(unsigned short s) {
    return __uint_as_float(((unsigned)s) << 16);
}

struct Frag2 { bf16x8 h, l; };

static __device__ inline Frag2 load_split(const float* __restrict__ p) {
    float4 x0 = *reinterpret_cast<const float4*>(p);
    float4 x1 = *reinterpret_cast<const float4*>(p + 4);
    float v[8] = {x0.x, x0.y, x0.z, x0.w, x1.x, x1.y, x1.z, x1.w};
    ushort8 uh, ul;
#pragma unroll
    for (int j = 0; j < 8; ++j) {
        unsigned short h = f2bf(v[j]);
        float r = v[j] - bf2f(h);
        uh[j] = h;
        ul[j] = f2bf(r);
    }
    Frag2 f;
    f.h = __builtin_bit_cast(bf16x8, uh);
    f.l = __builtin_bit_cast(bf16x8, ul);
    return f;
}

static __device__ inline bf16x8 pack_bf8(float4 x0, float4 x1) {
    float v[8] = {x0.x, x0.y, x0.z, x0.w, x1.x, x1.y, x1.z, x1.w};
    ushort8 u;
#pragma unroll
    for (int j = 0; j < 8; ++j) u[j] = f2bf(v[j]);
    return __builtin_bit_cast(bf16x8, u);
}

static __device__ inline bf16x8 load_bf8(const float* __restrict__ p) {
    float4 x0 = *reinterpret_cast<const float4*>(p);
    float4 x1 = *reinterpret_cast<const float4*>(p + 4);
    return pack_bf8(x0, x1);
}

static __device__ inline bf16x8 load_bf8_strided(const float* __restrict__ p, int stride) {
    ushort8 u;
#pragma unroll
    for (int j = 0; j < 8; ++j) u[j] = f2bf(p[(size_t)j * stride]);
    return __builtin_bit_cast(bf16x8, u);
}

#define MFMA(a, b, c) __builtin_amdgcn_mfma_f32_16x16x32_bf16((a), (b), (c), 0, 0, 0)

// async global -> LDS, 16B per lane; lds dest is wave-uniform base + lane*16
#define GLLD(g, s)                                                              \
    __builtin_amdgcn_global_load_lds(                                           \
        (const __attribute__((address_space(1))) void*)(g),                     \
        (__attribute__((address_space(3))) void*)(s), 16, 0, 0)

// stage a 64x64 fp32 tile (rows at src0 + row*DH) into buf[b], source
// pre-swizzled (chunk ^= row&7) so linear LDS + swizzled reads match.
#define STAGE64(src0, b)                                                        \
    do {                                                                        \
        _Pragma("unroll")                                                       \
        for (int j_ = 0; j_ < 4; ++j_) {                                        \
            const int idx_ = w * 256 + j_ * 64 + l;                             \
            const int row_ = idx_ >> 4;                                         \
            const int g_ = (idx_ & 15) ^ (row_ & 7);                            \
            GLLD((src0) + (size_t)row_ * DH + g_ * 4,                           \
                 &buf[b][w * 256 + j_ * 64]);                                   \
        }                                                                       \
    } while (0)

// ---------------- K1: content scores Q@K^T * scale -> P (zeros above diag).
// Block = (q-tile 64, bh). A = K k-rows (LDS, single bf16), B = Q q-rows
// (split bf16). C lane map: k = t*64 + w*16 + lg*4 + r, q = q0 + nt*16 + lm.
__global__ __launch_bounds__(256, 4) void k_scores(const float* __restrict__ qp,
                                                   const float* __restrict__ kp,
                                                   float* __restrict__ P) {
    __shared__ float4 buf[2][1024];
    const int qt = 15 - (int)blockIdx.x;  // big first
    const int bh = blockIdx.y;
    const int tid = threadIdx.x;
    const int w = tid >> 6, l = tid & 63;
    const int lm = l & 15, lg = l >> 4;
    const int q0 = qt * 64;

    Frag2 qh0[4], qh1[4];
#pragma unroll
    for (int nt = 0; nt < 4; ++nt) {
        const float* qrow = qp + ((size_t)bh * SQ + q0 + nt * 16 + lm) * DH + lg * 8;
        qh0[nt] = load_split(qrow);
        qh1[nt] = load_split(qrow + 32);
    }
    const float* kb = kp + (size_t)bh * SK * DH;
    const int nt_ = qt + 1;

    STAGE64(kb, 0);
#pragma unroll 1
    for (int t = 0; t < nt_; ++t) {
        if (t + 1 < nt_) STAGE64(kb + (size_t)(t + 1) * 64 * DH, (t + 1) & 1);
        __syncthreads();
        const float4* L = buf[t & 1];
        const int R = w * 16 + lm;
        const int sw = R & 7;
        float4 f0 = L[R * 16 + ((2 * lg) ^ sw)];
        float4 f1 = L[R * 16 + ((2 * lg + 1) ^ sw)];
        float4 f2 = L[R * 16 + ((8 + 2 * lg) ^ sw)];
        float4 f3 = L[R * 16 + ((9 + 2 * lg) ^ sw)];
        bf16x8 alo = pack_bf8(f0, f1);
        bf16x8 ahi = pack_bf8(f2, f3);
        const int kq = t * 64 + w * 16 + lg * 4;
        const bool diag = (t == qt);
#pragma unroll
        for (int nt = 0; nt < 4; ++nt) {
            f32x4 acc = {0.f, 0.f, 0.f, 0.f};
            acc = MFMA(alo, qh0[nt].h, acc);
            acc = MFMA(alo, qh0[nt].l, acc);
            acc = MFMA(ahi, qh1[nt].h, acc);
            acc = MFMA(ahi, qh1[nt].l, acc);
            const int qe = q0 + nt * 16 + lm;
            float ov[4];
#pragma unroll
            for (int r = 0; r < 4; ++r) {
                float v = acc[r] * SCALE;
                ov[r] = (!diag || (kq + r <= qe)) ? v : 0.f;
            }
            float4 o;
            o.x = ov[0]; o.y = ov[1]; o.z = ov[2]; o.w = ov[3];
            *reinterpret_cast<float4*>(&P[((size_t)bh * SQ + qe) * SK + kq]) = o;
        }
        __syncthreads();
    }
    // zero-fill tiles fully above the diagonal
    const float4 z = {0.f, 0.f, 0.f, 0.f};
#pragma unroll 1
    for (int t = nt_; t < 16; ++t) {
        const int kq = t * 64 + w * 16 + lg * 4;
#pragma unroll
        for (int nt = 0; nt < 4; ++nt) {
            const int qe = q0 + nt * 16 + lm;
            *reinterpret_cast<float4*>(&P[((size_t)bh * SQ + qe) * SK + kq]) = z;
        }
    }
}

// ---------------- K2: fused rel+exp+normalize+P@bigr_v. Block per q.
__global__ __launch_bounds__(256, 4) void k_rel_pr(const float* __restrict__ query,
                                                   const float* __restrict__ bigr_k,
                                                   const float* __restrict__ bigr_v,
                                                   float* __restrict__ P,
                                                   float* __restrict__ out) {
    __shared__ float4 buf[2][1024];  // pass1: bigr_k tiles; pass2: reused as vt
    __shared__ float red[4][64];
    __shared__ float rsum[64];
    const int q = SQ - 1 - (int)blockIdx.x;  // big rows first
    const int KE = q + 1;
    const int nt_ = (KE + 63) >> 6;
    const int tid = threadIdx.x;
    const int w = tid >> 6, l = tid & 63;
    const int lm = l & 15, lg = l >> 4;

    // ---- pass 1: e = exp(content + rel), row sums ----
    Frag2 qh0[4], qh1[4];
    float* prow[4];
#pragma unroll
    for (int nt = 0; nt < 4; ++nt) {
        const int bh = nt * 16 + lm;
        const float* qrow = query + ((size_t)bh * SQ + q) * DH + lg * 8;
        qh0[nt] = load_split(qrow);
        qh1[nt] = load_split(qrow + 32);
        prow[nt] = P + ((size_t)bh * SQ + q) * SK;
    }
    const float* bk = bigr_k + (size_t)q * SK * DH;
    float lsum[4] = {0.f, 0.f, 0.f, 0.f};

    STAGE64(bk, 0);
    float4 pc[4];
#pragma unroll 1
    for (int t = 0; t < nt_; ++t) {
        if (t + 1 < nt_) STAGE64(bk + (size_t)(t + 1) * 64 * DH, (t + 1) & 1);
        const int kq = t * 64 + w * 16 + lg * 4;
#pragma unroll
        for (int nt = 0; nt < 4; ++nt)
            pc[nt] = *reinterpret_cast<const float4*>(prow[nt] + kq);
        __syncthreads();
        const float4* L = buf[t & 1];
        const int R = w * 16 + lm;
        const int sw = R & 7;
        float4 f0 = L[R * 16 + ((2 * lg) ^ sw)];
        float4 f1 = L[R * 16 + ((2 * lg + 1) ^ sw)];
        float4 f2 = L[R * 16 + ((8 + 2 * lg) ^ sw)];
        float4 f3 = L[R * 16 + ((9 + 2 * lg) ^ sw)];
        bf16x8 alo = pack_bf8(f0, f1);
        bf16x8 ahi = pack_bf8(f2, f3);
#pragma unroll
        for (int nt = 0; nt < 4; ++nt) {
            f32x4 acc = {0.f, 0.f, 0.f, 0.f};
            acc = MFMA(alo, qh0[nt].h, acc);
            acc = MFMA(alo, qh0[nt].l, acc);
            acc = MFMA(ahi, qh1[nt].h, acc);
            acc = MFMA(ahi, qh1[nt].l, acc);
            const float4 c = pc[nt];
            float cv[4] = {c.x, c.y, c.z, c.w};
            float ov[4];
#pragma unroll
            for (int r = 0; r < 4; ++r) {
                float e = (kq + r < KE) ? __expf(cv[r] + acc[r] * SCALE) : 0.f;
                ov[r] = e;
                lsum[nt] += e;
            }
            float4 o;
            o.x = ov[0]; o.y = ov[1]; o.z = ov[2]; o.w = ov[3];
            *reinterpret_cast<float4*>(prow[nt] + kq) = o;
        }
        __syncthreads();
    }

    // ---- row-sum reduce -> recip in LDS ----
#pragma unroll
    for (int nt = 0; nt < 4; ++nt) {
        float v = lsum[nt];
        v += __shfl_xor(v, 16);
        v += __shfl_xor(v, 32);
        if (l < 16) red[w][nt * 16 + l] = v;
    }
    __syncthreads();
    if (tid < 64)
        rsum[tid] = 1.0f / (red[0][tid] + red[1][tid] + red[2][tid] + red[3][tid]);

    // ---- pass 2: normalize P in place + out = Pn @ bigr_v[q] ----
    float* vtf = reinterpret_cast<float*>(&buf[0][0]);  // [64][36] transposed tile
    const int bh0 = w * 16;
    const int skk = tid & 31, sdd = (tid >> 5) * 8;
    const float* bv = bigr_v + (size_t)q * SK * DH;
    float* arow0 = P + ((size_t)(bh0 + lm) * SQ + q) * SK + lg * 8;
    f32x4 acc[4] = {{0.f,0.f,0.f,0.f},{0.f,0.f,0.f,0.f},{0.f,0.f,0.f,0.f},{0.f,0.f,0.f,0.f}};
#pragma unroll 1
    for (int k0 = 0; k0 < KE; k0 += 32) {
        __syncthreads();
        {   // stage bigr_v[q][k0+skk][sdd..+8] -> vtf[d][k] (transpose)
            const float* src = bv + (size_t)(k0 + skk) * DH + sdd;
            float4 v0 = *reinterpret_cast<const float4*>(src);
            float4 v1 = *reinterpret_cast<const float4*>(src + 4);
            vtf[(sdd + 0) * 36 + skk] = v0.x; vtf[(sdd + 1) * 36 + skk] = v0.y;
            vtf[(sdd + 2) * 36 + skk] = v0.z; vtf[(sdd + 3) * 36 + skk] = v0.w;
            vtf[(sdd + 4) * 36 + skk] = v1.x; vtf[(sdd + 5) * 36 + skk] = v1.y;
            vtf[(sdd + 6) * 36 + skk] = v1.z; vtf[(sdd + 7) * 36 + skk] = v1.w;
        }
        __syncthreads();
        const float nrm = rsum[bh0 + lm];
        float* arow = arow0 + k0;
        float4 x0 = *reinterpret_cast<const float4*>(arow);
        float4 x1 = *reinterpret_cast<const float4*>(arow + 4);
        float4 y0 = {x0.x * nrm, x0.y * nrm, x0.z * nrm, x0.w * nrm};
        float4 y1 = {x1.x * nrm, x1.y * nrm, x1.z * nrm, x1.w * nrm};
        *reinterpret_cast<float4*>(arow) = y0;       // final normalized p_attn
        *reinterpret_cast<float4*>(arow + 4) = y1;
        bf16x8 a = pack_bf8(y0, y1);
#pragma unroll
        for (int nt = 0; nt < 4; ++nt) {
            const float* bp = &vtf[(nt * 16 + lm) * 36 + lg * 8];
            float4 u0 = *reinterpret_cast<const float4*>(bp);
            float4 u1 = *reinterpret_cast<const float4*>(bp + 4);
            acc[nt] = MFMA(a, pack_bf8(u0, u1), acc[nt]);
        }
    }
#pragma unroll
    for (int nt = 0; nt < 4; ++nt)
#pragma unroll
        for (int r = 0; r < 4; ++r)
            out[((size_t)(bh0 + lg * 4 + r) * SQ + q) * DH + nt * 16 + lm] = acc[nt][r];
}

// ---------------- K3: out += Pn @ V (per bh, q-tiles of 64)
__global__ __launch_bounds__(256) void k_pv(const float* __restrict__ P,
                                            const float* __restrict__ V,
                                            float* __restrict__ out) {
    const int qt = 15 - (int)blockIdx.x;  // big tiles first
    const int bh = blockIdx.y;
    const int tid = threadIdx.x;
    const int w = tid >> 6, l = tid & 63;
    const int lm = l & 15, lg = l >> 4;
    const int q0 = qt * 64 + w * 16;

    f32x4 acc[4] = {{0.f,0.f,0.f,0.f},{0.f,0.f,0.f,0.f},{0.f,0.f,0.f,0.f},{0.f,0.f,0.f,0.f}};
    const int kend = q0 + 16;
    for (int k0 = 0; k0 < kend; k0 += 32) {
        const float* arow = P + ((size_t)bh * SQ + q0 + lm) * SK + k0 + lg * 8;
        bf16x8 a = load_bf8(arow);
#pragma unroll
        for (int nt = 0; nt < 4; ++nt) {
            const float* bcol = V + ((size_t)bh * SK + k0 + lg * 8) * DH + nt * 16 + lm;
            bf16x8 b = load_bf8_strided(bcol, DH);
            acc[nt] = MFMA(a, b, acc[nt]);
        }
    }
#pragma unroll
    for (int nt = 0; nt < 4; ++nt)
#pragma unroll
        for (int r = 0; r < 4; ++r)
            out[((size_t)bh * SQ + q0 + lg * 4 + r) * DH + nt * 16 + lm] += acc[nt][r];
}

extern "C" void kernel_launch(void* const* d_in, const int* in_sizes, int n_in,
                              void* d_out, int out_size, void* d_ws, size_t ws_size,
                              hipStream_t stream) {
    const float* query  = (const float*)d_in[0];
    const float* key    = (const float*)d_in[1];
    const float* value  = (const float*)d_in[2];
    const float* bigr_k = (const float*)d_in[3];
    const float* bigr_v = (const float*)d_in[4];
    float* out = (float*)d_out;                       // BH*SQ*DH
    float* P   = out + (size_t)BH * SQ * DH;          // BH*SQ*SK

    k_scores<<<dim3(16, BH), 256, 0, stream>>>(query, key, P);
    k_rel_pr<<<dim3(SQ), 256, 0, stream>>>(query, bigr_k, bigr_v, P, out);
    k_pv<<<dim3(16, BH), 256, 0, stream>>>(P, value, out);
}